// Round 1
// baseline (6780.958 us; speedup 1.0000x reference)
//
#include <hip/hip_runtime.h>
#include <math.h>

#define Nn     512
#define Ll     500
#define TSTEPS 800
#define NWG    64
#define NJ     8      // source nodes per workgroup
#define NT     256
#define NEEG   64
#define NB_    40     // outer scan length (B)
#define NH_    20     // inner scan length (H)

// d_ws layout in floats
#define OFF_SUMSQ  0
#define OFF_ABORT  1
#define OFF_FLAGS  64        // 64 u32
#define OFF_ROWSUM 192       // 512
#define OFF_EEG    768       // 2560
#define OFF_WS     4096      // 512*512
#define OFF_PART   266240    // 2*512*64
#define OFF_LMT    331776    // 64*512

__device__ __forceinline__ float relu_(float x) { return fmaxf(x, 0.0f); }

// ws[i][j] = log1p(0.5*(exp(wbb_ij)*sc_ij + exp(wbb_ji)*sc_ji)); also row sums and global sumsq
__global__ void k_ws(const float* __restrict__ wbb, const float* __restrict__ sc,
                     float* __restrict__ ws)
{
    int i = blockIdx.x, tid = threadIdx.x;
    float rs = 0.f, sq = 0.f;
    for (int j = tid; j < Nn; j += NT) {
        float wij = expf(wbb[i*Nn+j]) * sc[i*Nn+j];
        float wji = expf(wbb[j*Nn+i]) * sc[j*Nn+i];
        float v = log1pf(0.5f*(wij + wji));
        ws[OFF_WS + i*Nn + j] = v;
        rs += v; sq += v*v;
    }
    #pragma unroll
    for (int off = 32; off > 0; off >>= 1) { rs += __shfl_down(rs, off); sq += __shfl_down(sq, off); }
    __shared__ float srs[4], ssq[4];
    int wv = tid >> 6, ln = tid & 63;
    if (ln == 0) { srs[wv] = rs; ssq[wv] = sq; }
    __syncthreads();
    if (tid == 0) {
        ws[OFF_ROWSUM + i] = srs[0]+srs[1]+srs[2]+srs[3];
        atomicAdd(&ws[OFF_SUMSQ], ssq[0]+ssq[1]+ssq[2]+ssq[3]);
    }
}

// lm_t = lm - column mean over EEG rows
__global__ void k_lmt(const float* __restrict__ lm, float* __restrict__ ws)
{
    int n = blockIdx.x*NT + threadIdx.x;
    if (n >= Nn) return;
    float s = 0.f;
    for (int e = 0; e < NEEG; ++e) s += lm[e*Nn + n];
    float mean = s * (1.0f/NEEG);
    for (int e = 0; e < NEEG; ++e) ws[OFF_LMT + e*Nn + n] = lm[e*Nn + n] - mean;
}

__global__ __launch_bounds__(NT) void k_main(
    const float* __restrict__ input, const float* __restrict__ noise_in,
    const float* __restrict__ hx, const float* __restrict__ hE,
    const float* __restrict__ dist, const float* __restrict__ W_in,
    const float* __restrict__ theta, float* __restrict__ ws)
{
    __shared__ float hist[NJ][512];          // 16 KB  circular E-history of owned nodes
    __shared__ float wn[NJ][Nn];             // 16 KB  w_n rows (symmetric) of owned nodes
    __shared__ unsigned short dd[NJ][Nn];    //  8 KB  delays[j][i]
    __shared__ float noise_l[NJ][TSTEPS];    // 25.6 KB noise ch0, step-ordered
    __shared__ float u_l[TSTEPS*2];          //  6.4 KB stimulus, step-ordered
    __shared__ float st[NJ][6];              // M,E,I,Mv,Ev,Iv
    __shared__ float led[NJ];
    __shared__ float lmt_l[NEEG][NJ];
    __shared__ float win_l[NJ][2];
    __shared__ float dgd[NJ];
    __shared__ unsigned abort_s;

    const int w   = blockIdx.x;
    const int tid = threadIdx.x;
    const int j0  = w*NJ;

    float th[16];
    #pragma unroll
    for (int k = 0; k < 16; ++k) th[k] = theta[k];
    const float kg   = 0.01f + relu_(th[0]);
    const float kc1  = 0.01f + relu_(th[1]);
    const float kc2  = 0.01f + relu_(th[2]);
    const float kc3  = 0.01f + relu_(th[3]);
    const float kc4  = 0.01f + relu_(th[4]);
    const float kstd = 150.0f + relu_(th[5]);
    const float rA   = relu_(th[6]);
    const float aa   = 1.0f + relu_(th[7]);
    const float rB   = relu_(th[8]);
    const float ab   = 1.0f + relu_(th[9]);
    const float vmax = th[10], v0p = th[11], rr = th[12];
    const float den  = 1.5f + relu_(th[15]);
    const float invnorm = 1.0f / sqrtf(ws[OFF_SUMSQ]);

    for (int idx = tid; idx < NJ*Nn; idx += NT) {
        int jl = idx >> 9, i = idx & 511;
        int jg = j0 + jl;
        wn[jl][i] = ws[OFF_WS + jg*Nn + i] * invnorm;
        dd[jl][i] = (unsigned short)(int)(dist[jg*Nn + i] / den);
    }
    // slot s holds E(tau) with s = tau mod 512; initial history: tau=-1-k -> hE[:,k]
    for (int idx = tid; idx < NJ*512; idx += NT) {
        int jl = idx >> 9, s = idx & 511;
        int k = 511 - s;
        hist[jl][s] = (k < Ll) ? hE[(j0+jl)*Ll + k] : 0.0f;
    }
    for (int idx = tid; idx < NJ*TSTEPS; idx += NT) {
        int jl = idx / TSTEPS, t = idx % TSTEPS;
        int tt = (t % NH_)*NB_ + (t / NH_);           // (h,b) -> h*B+b with b=t/20,h=t%20
        noise_l[jl][t] = noise_in[(j0+jl)*(NH_*NB_*3) + tt*3];
    }
    for (int idx = tid; idx < TSTEPS*2; idx += NT) {
        int t = idx >> 1, s = idx & 1;
        int tt = (t % NH_)*NB_ + (t / NH_);
        u_l[idx] = input[tt*2 + s];
    }
    if (tid < NJ*6) { int jl = tid/6, c = tid - jl*6; st[jl][c] = hx[(j0+jl)*6 + c]; }
    if (tid < NJ*2) { int jl = tid>>1; win_l[jl][tid&1] = W_in[(j0+jl)*2 + (tid&1)]; }
    if (tid < NJ)   { dgd[tid] = -ws[OFF_ROWSUM + j0 + tid] * invnorm; }
    for (int idx = tid; idx < NEEG*NJ; idx += NT) {
        int e = idx / NJ, jl = idx - e*NJ;
        lmt_l[e][jl] = ws[OFF_LMT + e*Nn + j0 + jl];
    }
    if (tid == 0) abort_s = 0u;
    __syncthreads();

    float*    part   = ws + OFF_PART;
    unsigned* flags  = (unsigned*)(ws + OFF_FLAGS);
    unsigned* abortf = (unsigned*)(ws + OFF_ABORT);

    for (int t = 0; t < TSTEPS; ++t) {
        const int parity = t & 1;
        const unsigned want = (unsigned)(t + 1);
        float* pb = part + parity*(Nn*NWG);

        // phase 1: partial coupling sums over owned sources for ALL targets (pure LDS)
        float acc0 = 0.f, acc1 = 0.f;
        {
            const int i0a = tid, i1a = tid + NT;
            #pragma unroll
            for (int jl = 0; jl < NJ; ++jl) {
                int s0 = (t - 1 - (int)dd[jl][i0a] + 512) & 511;
                int s1 = (t - 1 - (int)dd[jl][i1a] + 512) & 511;
                acc0 += wn[jl][i0a] * hist[jl][s0];
                acc1 += wn[jl][i1a] * hist[jl][s1];
            }
        }
        __hip_atomic_store(&pb[(tid     )*NWG + w], acc0, __ATOMIC_RELAXED, __HIP_MEMORY_SCOPE_AGENT);
        __hip_atomic_store(&pb[(tid + NT)*NWG + w], acc1, __ATOMIC_RELAXED, __HIP_MEMORY_SCOPE_AGENT);
        __threadfence();                 // every thread drains its own stores to LLC
        __syncthreads();
        if (tid == 0)
            __hip_atomic_store(&flags[w], want, __ATOMIC_RELEASE, __HIP_MEMORY_SCOPE_AGENT);

        // phase 2: wait for all WGs (lane per flag), with abort safety net
        if (tid < NWG) {
            unsigned spins = 0;
            while (__hip_atomic_load(&flags[tid], __ATOMIC_RELAXED, __HIP_MEMORY_SCOPE_AGENT) < want) {
                ++spins;
                if ((spins & 0x3FFu) == 0u) {
                    if (__hip_atomic_load(abortf, __ATOMIC_RELAXED, __HIP_MEMORY_SCOPE_AGENT) != 0u) { abort_s = 1u; break; }
                    if (spins > (1u<<27)) { __hip_atomic_store(abortf, 1u, __ATOMIC_RELAXED, __HIP_MEMORY_SCOPE_AGENT); abort_s = 1u; break; }
                }
            }
        }
        __syncthreads();
        if (abort_s) break;

        // phase 3: reduce the 64 partials for each owned node (wave-wide shuffle)
        {
            int ln = tid & 63, wv = tid >> 6;
            float va = __hip_atomic_load(&pb[(j0 + wv    )*NWG + ln], __ATOMIC_RELAXED, __HIP_MEMORY_SCOPE_AGENT);
            float vb = __hip_atomic_load(&pb[(j0 + wv + 4)*NWG + ln], __ATOMIC_RELAXED, __HIP_MEMORY_SCOPE_AGENT);
            #pragma unroll
            for (int off = 32; off > 0; off >>= 1) { va += __shfl_down(va, off); vb += __shfl_down(vb, off); }
            if (ln == 0) { led[wv] = va; led[wv+4] = vb; }
        }
        __syncthreads();

        // phase 4: node-local ODE step for owned nodes
        if (tid < NJ) {
            const int jl = tid;
            float M = st[jl][0], E = st[jl][1], I = st[jl][2];
            float Mv = st[jl][3], Ev = st[jl][4], Iv = st[jl][5];
            float LEd = led[jl];
            float noiseE = noise_l[jl][t];
            float stim = win_l[jl][0]*u_l[2*t] + win_l[jl][1]*u_l[2*t+1];
            float rM   = vmax / (1.0f + expf(-rr*((E - I)   - v0p)));
            float s1v  = vmax / (1.0f + expf(-rr*((kc1*M)   - v0p)));
            float s3v  = vmax / (1.0f + expf(-rr*((kc3*M)   - v0p)));
            float rE = kstd*noiseE + kg*(LEd + dgd[jl]*E) + kc2*s1v;
            float rI = kc4*s3v;
            float nM = M + 0.05f*Mv, nE = E + 0.05f*Ev, nI = I + 0.05f*Iv;
            float nMv = Mv + 0.05f*(rA*aa*(500.0f*tanhf(rM*0.002f)) - 2.0f*aa*Mv - aa*aa*M);
            float nEv = Ev + 0.05f*(rA*aa*(stim + 500.0f*tanhf(rE*0.002f)) - 2.0f*aa*Ev - aa*aa*E);
            float nIv = Iv + 0.05f*(rB*ab*(500.0f*tanhf(rI*0.002f)) - 2.0f*ab*Iv - ab*ab*I);
            st[jl][0] = nM; st[jl][1] = nE; st[jl][2] = nI;
            st[jl][3] = nMv; st[jl][4] = nEv; st[jl][5] = nIv;
            hist[jl][t & 511] = nE;
        }
        __syncthreads();

        // phase 5: EEG partial at inner-scan boundary (every NH_ steps)
        if (((t+1) % NH_) == 0 && tid < NEEG) {
            int bo = t / NH_;
            float s = 0.f;
            #pragma unroll
            for (int jl = 0; jl < NJ; ++jl) s += lmt_l[tid][jl]*(st[jl][1] - st[jl][2]);
            atomicAdd(&ws[OFF_EEG + bo*NEEG + tid], s);
        }
    }
}

__global__ void k_out(const float* __restrict__ ws, const float* __restrict__ theta,
                      float* __restrict__ out)
{
    int idx = blockIdx.x*NT + threadIdx.x;
    if (idx < NB_*NEEG) out[idx] = 0.01f*theta[13]*ws[OFF_EEG + idx] - theta[14];
}

extern "C" void kernel_launch(void* const* d_in, const int* in_sizes, int n_in,
                              void* d_out, int out_size, void* d_ws, size_t ws_size,
                              hipStream_t stream)
{
    const float* input    = (const float*)d_in[0];
    const float* noise_in = (const float*)d_in[1];
    const float* hx       = (const float*)d_in[3];
    const float* hE       = (const float*)d_in[4];
    const float* sc       = (const float*)d_in[5];
    const float* dist     = (const float*)d_in[6];
    const float* w_bb     = (const float*)d_in[7];
    const float* W_in     = (const float*)d_in[8];
    const float* lm       = (const float*)d_in[10];
    const float* theta    = (const float*)d_in[11];
    float* ws  = (float*)d_ws;
    float* out = (float*)d_out;

    hipMemsetAsync(d_ws, 0, OFF_WS*sizeof(float), stream);     // sumsq/abort/flags/rowsum/eeg acc
    k_ws  <<<Nn, NT, 0, stream>>>(w_bb, sc, ws);
    k_lmt <<<(Nn + NT - 1)/NT, NT, 0, stream>>>(lm, ws);
    k_main<<<NWG, NT, 0, stream>>>(input, noise_in, hx, hE, dist, W_in, theta, ws);
    k_out <<<(NB_*NEEG + NT - 1)/NT, NT, 0, stream>>>(ws, theta, out);
}

// Round 2
// 3127.520 us; speedup vs baseline: 2.1682x; 2.1682x over previous
//
#include <hip/hip_runtime.h>
#include <math.h>

#define Nn     512
#define Ll     500
#define TSTEPS 800
#define NWG    64
#define NJ     8      // source nodes per workgroup
#define NT     256
#define NEEG   64
#define NB_    40     // outer scan length (B)
#define NH_    20     // inner scan length (H)
#define ND0CAP 256    // max delay-0 entries per WG (expected ~9)

// d_ws layout in floats
#define OFF_SUMSQ  0
#define OFF_ABORT  1
#define OFF_CNT    2
#define OFF_ROWSUM 64          // 512
#define OFF_EEG    768         // 2560
#define OFF_ACC    3328        // 2*512
#define OFF_ZEND   4352        // memset range end
#define OFF_WS     4608        // 512*512
#define OFF_LMT    (OFF_WS + Nn*Nn)  // 64*512

__device__ __forceinline__ float relu_(float x) { return fmaxf(x, 0.0f); }

// ws[i][j] = log1p(0.5*(exp(wbb_ij)*sc_ij + exp(wbb_ji)*sc_ji)); row sums; global sumsq
__global__ void k_ws(const float* __restrict__ wbb, const float* __restrict__ sc,
                     float* __restrict__ ws)
{
    int i = blockIdx.x, tid = threadIdx.x;
    float rs = 0.f, sq = 0.f;
    for (int j = tid; j < Nn; j += NT) {
        float wij = expf(wbb[i*Nn+j]) * sc[i*Nn+j];
        float wji = expf(wbb[j*Nn+i]) * sc[j*Nn+i];
        float v = log1pf(0.5f*(wij + wji));
        ws[OFF_WS + i*Nn + j] = v;
        rs += v; sq += v*v;
    }
    #pragma unroll
    for (int off = 32; off > 0; off >>= 1) { rs += __shfl_down(rs, off); sq += __shfl_down(sq, off); }
    __shared__ float srs[4], ssq[4];
    int wv = tid >> 6, ln = tid & 63;
    if (ln == 0) { srs[wv] = rs; ssq[wv] = sq; }
    __syncthreads();
    if (tid == 0) {
        ws[OFF_ROWSUM + i] = srs[0]+srs[1]+srs[2]+srs[3];
        atomicAdd(&ws[OFF_SUMSQ], ssq[0]+ssq[1]+ssq[2]+ssq[3]);
    }
}

__global__ void k_lmt(const float* __restrict__ lm, float* __restrict__ ws)
{
    int n = blockIdx.x*NT + threadIdx.x;
    if (n >= Nn) return;
    float s = 0.f;
    for (int e = 0; e < NEEG; ++e) s += lm[e*Nn + n];
    float mean = s * (1.0f/NEEG);
    for (int e = 0; e < NEEG; ++e) ws[OFF_LMT + e*Nn + n] = lm[e*Nn + n] - mean;
}

__global__ __launch_bounds__(NT) void k_main(
    const float* __restrict__ input, const float* __restrict__ noise_in,
    const float* __restrict__ hx, const float* __restrict__ hE,
    const float* __restrict__ dist, const float* __restrict__ W_in,
    const float* __restrict__ theta, float* __restrict__ ws)
{
    __shared__ float hist[NJ][512];          // circular E-history of owned nodes
    __shared__ float wn[NJ][Nn];             // w_n rows (symmetric), d0 entries zeroed
    __shared__ unsigned short dd[NJ][Nn];    // delays[j][i]
    __shared__ float noise_l[NJ][TSTEPS];
    __shared__ float u_l[TSTEPS*2];
    __shared__ float st[NJ][6];              // M,E,I,Mv,Ev,Iv
    __shared__ float lmt_l[NEEG][NJ];
    __shared__ float win_l[NJ][2];
    __shared__ float dgd[NJ];
    __shared__ float eeg_l[NB_][NEEG];
    __shared__ int   d0_pk[ND0CAP];          // (jl<<16)|i
    __shared__ float d0_w[ND0CAP];
    __shared__ int   nd0_s;
    __shared__ unsigned abort_s;

    const int w   = blockIdx.x;
    const int tid = threadIdx.x;
    const int j0  = w*NJ;

    float th[16];
    #pragma unroll
    for (int k = 0; k < 16; ++k) th[k] = theta[k];
    const float kg   = 0.01f + relu_(th[0]);
    const float kc1  = 0.01f + relu_(th[1]);
    const float kc2  = 0.01f + relu_(th[2]);
    const float kc3  = 0.01f + relu_(th[3]);
    const float kc4  = 0.01f + relu_(th[4]);
    const float kstd = 150.0f + relu_(th[5]);
    const float rA   = relu_(th[6]);
    const float aa   = 1.0f + relu_(th[7]);
    const float rB   = relu_(th[8]);
    const float ab   = 1.0f + relu_(th[9]);
    const float vmax = th[10], v0p = th[11], rr = th[12];
    const float den  = 1.5f + relu_(th[15]);
    const float invnorm = 1.0f / sqrtf(ws[OFF_SUMSQ]);

    if (tid == 0) { abort_s = 0u; nd0_s = 0; }

    for (int idx = tid; idx < NJ*Nn; idx += NT) {
        int jl = idx >> 9, i = idx & 511;
        int jg = j0 + jl;
        wn[jl][i] = ws[OFF_WS + jg*Nn + i] * invnorm;
        dd[jl][i] = (unsigned short)(int)(dist[jg*Nn + i] / den);
    }
    // slot s holds E(tau), s = tau mod 512; initial: tau=-1-k -> hE[:,k]
    for (int idx = tid; idx < NJ*512; idx += NT) {
        int jl = idx >> 9, s = idx & 511;
        int k = 511 - s;
        hist[jl][s] = (k < Ll) ? hE[(j0+jl)*Ll + k] : 0.0f;
    }
    for (int idx = tid; idx < NJ*TSTEPS; idx += NT) {
        int jl = idx / TSTEPS, t = idx % TSTEPS;
        int tt = (t % NH_)*NB_ + (t / NH_);          // b=t/20, h=t%20
        noise_l[jl][t] = noise_in[(j0+jl)*(NH_*NB_*3) + tt*3];
    }
    for (int idx = tid; idx < TSTEPS*2; idx += NT) {
        int t = idx >> 1, s = idx & 1;
        int tt = (t % NH_)*NB_ + (t / NH_);
        u_l[idx] = input[tt*2 + s];
    }
    if (tid < NJ*6) { int jl = tid/6, c = tid - jl*6; st[jl][c] = hx[(j0+jl)*6 + c]; }
    if (tid < NJ*2) { int jl = tid>>1; win_l[jl][tid&1] = W_in[(j0+jl)*2 + (tid&1)]; }
    if (tid < NJ)   { dgd[tid] = -ws[OFF_ROWSUM + j0 + tid] * invnorm; }
    for (int idx = tid; idx < NEEG*NJ; idx += NT) {
        int e = idx / NJ, jl = idx - e*NJ;
        lmt_l[e][jl] = ws[OFF_LMT + e*Nn + j0 + jl];
    }
    __syncthreads();

    // prologue gather: partials(0) = sum wn * E(-1-d), full (incl. d0), all from init hist
    float p0 = 0.f, p1 = 0.f;
    #pragma unroll
    for (int jl = 0; jl < NJ; ++jl) {
        int s0 = (511 - (int)dd[jl][tid    ]) & 511;
        int s1 = (511 - (int)dd[jl][tid+NT]) & 511;
        p0 += wn[jl][tid    ] * hist[jl][s0];
        p1 += wn[jl][tid+NT ] * hist[jl][s1];
    }
    // find delay-0 entries (will be recomputed each step with fresh E)
    for (int idx = tid; idx < NJ*Nn; idx += NT) {
        int jl = idx >> 9, i = idx & 511;
        if (dd[jl][i] == 0) {
            int pos = atomicAdd(&nd0_s, 1);
            if (pos < ND0CAP) { d0_pk[pos] = (jl<<16) | i; d0_w[pos] = wn[jl][i]; }
        }
    }
    __syncthreads();
    int nd0 = nd0_s;
    if (nd0 > ND0CAP) {   // never expected; fail loudly
        if (tid == 0) __hip_atomic_store((unsigned*)ws + OFF_ABORT, 1u, __ATOMIC_RELAXED, __HIP_MEMORY_SCOPE_AGENT);
        return;
    }
    for (int idx = tid; idx < nd0; idx += NT) {
        int pk = d0_pk[idx];
        wn[pk>>16][pk & 0xFFFF] = 0.f;       // mask d0 from the per-step gather
    }
    __syncthreads();

    float*    acc    = ws + OFF_ACC;
    unsigned* cntp   = (unsigned*)ws + OFF_CNT;
    unsigned* abortf = (unsigned*)ws + OFF_ABORT;

    // publish partials(0) into acc[0]
    __hip_atomic_fetch_add(&acc[tid    ], p0, __ATOMIC_RELAXED, __HIP_MEMORY_SCOPE_AGENT);
    __hip_atomic_fetch_add(&acc[tid+NT ], p1, __ATOMIC_RELAXED, __HIP_MEMORY_SCOPE_AGENT);
    asm volatile("s_waitcnt vmcnt(0)" ::: "memory");
    __syncthreads();
    if (tid == 0) __hip_atomic_fetch_add(cntp, 1u, __ATOMIC_RELAXED, __HIP_MEMORY_SCOPE_AGENT);

    for (int k = 0; k < TSTEPS; ++k) {
        const int p = k & 1;
        float* accCur = acc + p*Nn;
        float* accNxt = acc + (p^1)*Nn;
        const bool pub = (k < TSTEPS-1);

        // (1) gather partials(k+1): E(k-d), d>=1 entries only — pure local LDS, off critical path
        float g0 = 0.f, g1 = 0.f;
        #pragma unroll
        for (int jl = 0; jl < NJ; ++jl) {
            int s0 = (k - (int)dd[jl][tid    ]) & 511;
            int s1 = (k - (int)dd[jl][tid+NT]) & 511;
            g0 += wn[jl][tid    ] * hist[jl][s0];
            g1 += wn[jl][tid+NT ] * hist[jl][s1];
        }

        // (2) wait until all WGs finished step k-1 (=> partials(k) complete, acc[p^1] consumed+zeroed)
        if (tid == 0) {
            const unsigned target = 64u*(unsigned)(k+1);
            unsigned spins = 0;
            while (__hip_atomic_load(cntp, __ATOMIC_RELAXED, __HIP_MEMORY_SCOPE_AGENT) < target) {
                __builtin_amdgcn_s_sleep(1);
                if ((++spins & 1023u) == 0u) {
                    if (__hip_atomic_load(abortf, __ATOMIC_RELAXED, __HIP_MEMORY_SCOPE_AGENT) != 0u) { abort_s = 1u; break; }
                    if (spins > (1u<<22)) { __hip_atomic_store(abortf, 1u, __ATOMIC_RELAXED, __HIP_MEMORY_SCOPE_AGENT); abort_s = 1u; break; }
                }
            }
        }
        __syncthreads();
        if (abort_s) break;

        // (3) publish main partials(k+1) (fire-and-forget)
        if (pub) {
            __hip_atomic_fetch_add(&accNxt[tid    ], g0, __ATOMIC_RELAXED, __HIP_MEMORY_SCOPE_AGENT);
            __hip_atomic_fetch_add(&accNxt[tid+NT ], g1, __ATOMIC_RELAXED, __HIP_MEMORY_SCOPE_AGENT);
        }

        // (4) fetch reduced coupling (read+zero in one op) and step the ODEs
        if (tid < NJ) {
            const int jl = tid;
            float LEd = __hip_atomic_exchange(&accCur[j0+jl], 0.0f, __ATOMIC_RELAXED, __HIP_MEMORY_SCOPE_AGENT);
            float M = st[jl][0], E = st[jl][1], I = st[jl][2];
            float Mv = st[jl][3], Ev = st[jl][4], Iv = st[jl][5];
            float noiseE = noise_l[jl][k];
            float stim = win_l[jl][0]*u_l[2*k] + win_l[jl][1]*u_l[2*k+1];
            float rM   = vmax / (1.0f + expf(-rr*((E - I)   - v0p)));
            float s1v  = vmax / (1.0f + expf(-rr*((kc1*M)   - v0p)));
            float s3v  = vmax / (1.0f + expf(-rr*((kc3*M)   - v0p)));
            float rE = kstd*noiseE + kg*(LEd + dgd[jl]*E) + kc2*s1v;
            float rI = kc4*s3v;
            float nM = M + 0.05f*Mv, nE = E + 0.05f*Ev, nI = I + 0.05f*Iv;
            float nMv = Mv + 0.05f*(rA*aa*(500.0f*tanhf(rM*0.002f)) - 2.0f*aa*Mv - aa*aa*M);
            float nEv = Ev + 0.05f*(rA*aa*(stim + 500.0f*tanhf(rE*0.002f)) - 2.0f*aa*Ev - aa*aa*E);
            float nIv = Iv + 0.05f*(rB*ab*(500.0f*tanhf(rI*0.002f)) - 2.0f*ab*Iv - ab*ab*I);
            st[jl][0] = nM; st[jl][1] = nE; st[jl][2] = nI;
            st[jl][3] = nMv; st[jl][4] = nEv; st[jl][5] = nIv;
            hist[jl][k & 511] = nE;
        }
        __syncthreads();

        // (5) sparse d0 corrections with fresh E(k); EEG at inner-scan boundary
        if (pub && tid < nd0) {
            int pk = d0_pk[tid];
            __hip_atomic_fetch_add(&accNxt[pk & 0xFFFF],
                                   d0_w[tid]*hist[pk>>16][k & 511],
                                   __ATOMIC_RELAXED, __HIP_MEMORY_SCOPE_AGENT);
        }
        if (((k+1) % NH_) == 0 && tid < NEEG) {
            float s = 0.f;
            #pragma unroll
            for (int jl = 0; jl < NJ; ++jl) s += lmt_l[tid][jl]*(st[jl][1] - st[jl][2]);
            eeg_l[k/NH_][tid] = s;
        }

        // (6,7,8) drain own atomics, then signal step completion
        asm volatile("s_waitcnt vmcnt(0)" ::: "memory");
        __syncthreads();
        if (pub && tid == 0)
            __hip_atomic_fetch_add(cntp, 1u, __ATOMIC_RELAXED, __HIP_MEMORY_SCOPE_AGENT);
    }

    // flush per-WG EEG partials
    __syncthreads();
    if (!abort_s) {
        const float* el = &eeg_l[0][0];
        for (int idx = tid; idx < NB_*NEEG; idx += NT)
            __hip_atomic_fetch_add(&ws[OFF_EEG + idx], el[idx], __ATOMIC_RELAXED, __HIP_MEMORY_SCOPE_AGENT);
    }
}

__global__ void k_out(const float* __restrict__ ws, const float* __restrict__ theta,
                      float* __restrict__ out)
{
    int idx = blockIdx.x*NT + threadIdx.x;
    if (idx < NB_*NEEG) out[idx] = 0.01f*theta[13]*ws[OFF_EEG + idx] - theta[14];
}

extern "C" void kernel_launch(void* const* d_in, const int* in_sizes, int n_in,
                              void* d_out, int out_size, void* d_ws, size_t ws_size,
                              hipStream_t stream)
{
    const float* input    = (const float*)d_in[0];
    const float* noise_in = (const float*)d_in[1];
    const float* hx       = (const float*)d_in[3];
    const float* hE       = (const float*)d_in[4];
    const float* sc       = (const float*)d_in[5];
    const float* dist     = (const float*)d_in[6];
    const float* w_bb     = (const float*)d_in[7];
    const float* W_in     = (const float*)d_in[8];
    const float* lm       = (const float*)d_in[10];
    const float* theta    = (const float*)d_in[11];
    float* ws  = (float*)d_ws;
    float* out = (float*)d_out;

    hipMemsetAsync(d_ws, 0, OFF_ZEND*sizeof(float), stream);   // sumsq/abort/cnt/rowsum/eeg/acc
    k_ws  <<<Nn, NT, 0, stream>>>(w_bb, sc, ws);
    k_lmt <<<(Nn + NT - 1)/NT, NT, 0, stream>>>(lm, ws);
    k_main<<<NWG, NT, 0, stream>>>(input, noise_in, hx, hE, dist, W_in, theta, ws);
    k_out <<<(NB_*NEEG + NT - 1)/NT, NT, 0, stream>>>(ws, theta, out);
}

// Round 3
// 1859.840 us; speedup vs baseline: 3.6460x; 1.6816x over previous
//
#include <hip/hip_runtime.h>
#include <math.h>

#define Nn     512
#define Ll     500
#define TSTEPS 800
#define NWG    32
#define NJ     16     // source nodes per workgroup
#define NT     320    // 5 waves: wave0 = control, waves 1-4 = gather
#define NEEG   64
#define NB_    40     // outer scan length (B)
#define NH_    20     // inner scan length (H)
#define ND0CAP 128    // max delay-0 entries per WG (expected ~18)
#define FSTR   16     // flag stride in u32 (64B lines)

// d_ws layout in floats
#define OFF_SUMSQ  0
#define OFF_ABORT  1
#define OFF_FLAGS  16                   // 32 flags * FSTR u32 -> [16,528)
#define OFF_ROWSUM 544                  // 512
#define OFF_EEG    1056                 // 2560
#define OFF_ACC    3616                 // 3*512 rotating buffers
#define OFF_ZEND   5152                 // memset range end (floats)
#define OFF_WS     5184                 // 512*512
#define OFF_LMT    (OFF_WS + Nn*Nn)     // 64*512

__device__ __forceinline__ float relu_(float x) { return fmaxf(x, 0.0f); }

__global__ void k_ws(const float* __restrict__ wbb, const float* __restrict__ sc,
                     float* __restrict__ ws)
{
    int i = blockIdx.x, tid = threadIdx.x;
    float rs = 0.f, sq = 0.f;
    for (int j = tid; j < Nn; j += 256) {
        float wij = expf(wbb[i*Nn+j]) * sc[i*Nn+j];
        float wji = expf(wbb[j*Nn+i]) * sc[j*Nn+i];
        float v = log1pf(0.5f*(wij + wji));
        ws[OFF_WS + i*Nn + j] = v;
        rs += v; sq += v*v;
    }
    #pragma unroll
    for (int off = 32; off > 0; off >>= 1) { rs += __shfl_down(rs, off); sq += __shfl_down(sq, off); }
    __shared__ float srs[4], ssq[4];
    int wv = tid >> 6, ln = tid & 63;
    if (ln == 0) { srs[wv] = rs; ssq[wv] = sq; }
    __syncthreads();
    if (tid == 0) {
        ws[OFF_ROWSUM + i] = srs[0]+srs[1]+srs[2]+srs[3];
        atomicAdd(&ws[OFF_SUMSQ], ssq[0]+ssq[1]+ssq[2]+ssq[3]);
    }
}

__global__ void k_lmt(const float* __restrict__ lm, float* __restrict__ ws)
{
    int n = blockIdx.x*256 + threadIdx.x;
    if (n >= Nn) return;
    float s = 0.f;
    for (int e = 0; e < NEEG; ++e) s += lm[e*Nn + n];
    float mean = s * (1.0f/NEEG);
    for (int e = 0; e < NEEG; ++e) ws[OFF_LMT + e*Nn + n] = lm[e*Nn + n] - mean;
}

__global__ __launch_bounds__(NT) void k_main(
    const float* __restrict__ input, const float* __restrict__ noise_in,
    const float* __restrict__ hx, const float* __restrict__ hE,
    const float* __restrict__ dist, const float* __restrict__ W_in,
    const float* __restrict__ theta, float* __restrict__ ws)
{
    __shared__ float hist[NJ][512];          // 32 KB circular E-history
    __shared__ float wn[NJ][Nn];             // 32 KB weights (d0 zeroed after prologue)
    __shared__ unsigned short dd[NJ][Nn];    // 16 KB delays
    __shared__ float u_l[TSTEPS*2];          // 6.4 KB stimulus
    __shared__ float lmt_l[NEEG][NJ];        // 4 KB
    __shared__ float eeg_l[NB_][NEEG];       // 10.2 KB
    __shared__ float eim[NJ];                // E-I snapshot at EEG boundaries
    __shared__ int   d0_pk[ND0CAP];
    __shared__ float d0_w[ND0CAP];
    __shared__ int   nd0_s;
    __shared__ unsigned abort_s;

    const int w   = blockIdx.x;
    const int tid = threadIdx.x;
    const int j0  = w*NJ;

    float th[16];
    #pragma unroll
    for (int k = 0; k < 16; ++k) th[k] = theta[k];
    const float kg   = 0.01f + relu_(th[0]);
    const float kc1  = 0.01f + relu_(th[1]);
    const float kc2  = 0.01f + relu_(th[2]);
    const float kc3  = 0.01f + relu_(th[3]);
    const float kc4  = 0.01f + relu_(th[4]);
    const float kstd = 150.0f + relu_(th[5]);
    const float rA   = relu_(th[6]);
    const float aa   = 1.0f + relu_(th[7]);
    const float rB   = relu_(th[8]);
    const float ab   = 1.0f + relu_(th[9]);
    const float vmax = th[10], v0p = th[11], rr = th[12];
    const float den  = 1.5f + relu_(th[15]);
    const float invnorm = 1.0f / sqrtf(ws[OFF_SUMSQ]);

    if (tid == 0) { abort_s = 0u; nd0_s = 0; }

    for (int idx = tid; idx < NJ*Nn; idx += NT) {
        int jl = idx >> 9, i = idx & 511;
        int jg = j0 + jl;
        wn[jl][i] = ws[OFF_WS + jg*Nn + i] * invnorm;
        dd[jl][i] = (unsigned short)(int)(dist[jg*Nn + i] / den);
    }
    // slot s holds E(tau), s = tau mod 512; initial: tau=-1-k -> hE[:,k]
    for (int idx = tid; idx < NJ*512; idx += NT) {
        int jl = idx >> 9, s = idx & 511;
        int k = 511 - s;
        hist[jl][s] = (k < Ll) ? hE[(j0+jl)*Ll + k] : 0.0f;
    }
    for (int idx = tid; idx < TSTEPS*2; idx += NT) {
        int t = idx >> 1, s = idx & 1;
        int tt = (t % NH_)*NB_ + (t / NH_);
        u_l[idx] = input[tt*2 + s];
    }
    for (int idx = tid; idx < NEEG*NJ; idx += NT) {
        int e = idx / NJ, jl = idx - e*NJ;
        lmt_l[e][jl] = ws[OFF_LMT + e*Nn + j0 + jl];
    }
    // per-lane ODE state + params (wave 0, lanes < NJ)
    float stM=0,stE=0,stI=0,stMv=0,stEv=0,stIv=0, dgd_r=0, win0=0, win1=0;
    const float* nz_base = nullptr;
    if (tid < NJ) {
        stM  = hx[(j0+tid)*6+0]; stE  = hx[(j0+tid)*6+1]; stI  = hx[(j0+tid)*6+2];
        stMv = hx[(j0+tid)*6+3]; stEv = hx[(j0+tid)*6+4]; stIv = hx[(j0+tid)*6+5];
        dgd_r = -ws[OFF_ROWSUM + j0 + tid] * invnorm;
        win0 = W_in[(j0+tid)*2+0]; win1 = W_in[(j0+tid)*2+1];
        nz_base = noise_in + (size_t)(j0+tid)*(NH_*NB_*3);
    }
    __syncthreads();

    // d0 detection
    for (int idx = tid; idx < NJ*Nn; idx += NT) {
        int jl = idx >> 9, i = idx & 511;
        if (dd[jl][i] == 0) {
            int pos = atomicAdd(&nd0_s, 1);
            if (pos < ND0CAP) { d0_pk[pos] = (jl<<16) | i; d0_w[pos] = wn[jl][i]; }
        }
    }
    __syncthreads();
    const int nd0 = nd0_s;
    float*    acc    = ws + OFF_ACC;
    unsigned* flags  = (unsigned*)ws + OFF_FLAGS;
    unsigned* abortf = (unsigned*)ws + OFF_ABORT;
    if (nd0 > ND0CAP) {      // never expected; fail loudly
        if (tid == 0) __hip_atomic_store(abortf, 1u, __ATOMIC_RELAXED, __HIP_MEMORY_SCOPE_AGENT);
        return;
    }

    // prologue: partials(0) with FULL weights (incl. d0) from init history -> acc[0]
    if (tid >= 64) {
        int gt = tid - 64;
        float p0 = 0.f, p1 = 0.f;
        #pragma unroll
        for (int jl = 0; jl < NJ; ++jl) {
            int s0 = (511 - (int)dd[jl][gt    ]) & 511;
            int s1 = (511 - (int)dd[jl][gt+256]) & 511;
            p0 += wn[jl][gt    ] * hist[jl][s0];
            p1 += wn[jl][gt+256] * hist[jl][s1];
        }
        __hip_atomic_fetch_add(&acc[gt    ], p0, __ATOMIC_RELAXED, __HIP_MEMORY_SCOPE_AGENT);
        __hip_atomic_fetch_add(&acc[gt+256], p1, __ATOMIC_RELAXED, __HIP_MEMORY_SCOPE_AGENT);
    }
    asm volatile("s_waitcnt vmcnt(0)" ::: "memory");
    __syncthreads();
    // mask d0 edges out of the per-step gather
    for (int idx = tid; idx < nd0; idx += NT) {
        int pk = d0_pk[idx];
        wn[pk>>16][pk & 0xFFFF] = 0.f;
    }
    __syncthreads();
    if (tid == 0) __hip_atomic_store(&flags[w*FSTR], 1u, __ATOMIC_RELAXED, __HIP_MEMORY_SCOPE_AGENT);

    for (int t = 0; t < TSTEPS; ++t) {
        float* accCur = acc + (t % 3)*Nn;
        float* accNxt = acc + ((t+1) % 3)*Nn;
        const bool pub = (t < TSTEPS-1);

        if (tid >= 64) {
            // ---- gather waves: partials(t+1) for d>=1 edges, publish BEFORE the barrier ----
            int gt = tid - 64;
            float g0 = 0.f, g1 = 0.f;
            #pragma unroll
            for (int jl = 0; jl < NJ; ++jl) {
                int s0 = (t - (int)dd[jl][gt    ]) & 511;
                int s1 = (t - (int)dd[jl][gt+256]) & 511;
                g0 += wn[jl][gt    ] * hist[jl][s0];
                g1 += wn[jl][gt+256] * hist[jl][s1];
            }
            if (pub) {
                __hip_atomic_fetch_add(&accNxt[gt    ], g0, __ATOMIC_RELAXED, __HIP_MEMORY_SCOPE_AGENT);
                __hip_atomic_fetch_add(&accNxt[gt+256], g1, __ATOMIC_RELAXED, __HIP_MEMORY_SCOPE_AGENT);
            }
            asm volatile("s_waitcnt vmcnt(0)" ::: "memory");
        } else {
            // ---- control wave ----
            float nz = 0.f;
            if (tid < NJ) nz = nz_base[((t % NH_)*NB_ + (t / NH_))*3];   // prefetch, hidden by poll
            // poll per-WG flags (one lane per flag)
            {
                const unsigned tgt = (unsigned)(t + 1);
                int spins = 0;
                for (;;) {
                    unsigned f = __hip_atomic_load(&flags[(tid & 31)*FSTR], __ATOMIC_RELAXED, __HIP_MEMORY_SCOPE_AGENT);
                    if (__all(f >= tgt)) break;
                    if ((++spins & 255) == 0) {
                        if (__hip_atomic_load(abortf, __ATOMIC_RELAXED, __HIP_MEMORY_SCOPE_AGENT) != 0u) { abort_s = 1u; break; }
                        if (spins > (1<<22)) { __hip_atomic_store(abortf, 1u, __ATOMIC_RELAXED, __HIP_MEMORY_SCOPE_AGENT); abort_s = 1u; break; }
                    }
                }
            }
            if (!abort_s) {
                if (tid < NJ) {
                    float LEd = __hip_atomic_exchange(&accCur[j0+tid], 0.0f, __ATOMIC_RELAXED, __HIP_MEMORY_SCOPE_AGENT);
                    float stim = win0*u_l[2*t] + win1*u_l[2*t+1];
                    float rM   = vmax / (1.0f + expf(-rr*((stE - stI) - v0p)));
                    float s1v  = vmax / (1.0f + expf(-rr*((kc1*stM)  - v0p)));
                    float s3v  = vmax / (1.0f + expf(-rr*((kc3*stM)  - v0p)));
                    float rE = kstd*nz + kg*(LEd + dgd_r*stE) + kc2*s1v;
                    float rI = kc4*s3v;
                    float nM = stM + 0.05f*stMv, nE = stE + 0.05f*stEv, nI = stI + 0.05f*stIv;
                    float nMv = stMv + 0.05f*(rA*aa*(500.0f*tanhf(rM*0.002f)) - 2.0f*aa*stMv - aa*aa*stM);
                    float nEv = stEv + 0.05f*(rA*aa*(stim + 500.0f*tanhf(rE*0.002f)) - 2.0f*aa*stEv - aa*aa*stE);
                    float nIv = stIv + 0.05f*(rB*ab*(500.0f*tanhf(rI*0.002f)) - 2.0f*ab*stIv - ab*ab*stI);
                    stM = nM; stE = nE; stI = nI; stMv = nMv; stEv = nEv; stIv = nIv;
                    hist[tid][t & 511] = nE;
                    if (((t+1) % NH_) == 0) eim[tid] = nE - nI;
                }
                // sparse d0 corrections with fresh E(t)
                if (pub) {
                    for (int q = tid; q < nd0; q += 64) {
                        int pk = d0_pk[q];
                        __hip_atomic_fetch_add(&accNxt[pk & 0xFFFF],
                                               d0_w[q]*hist[pk>>16][t & 511],
                                               __ATOMIC_RELAXED, __HIP_MEMORY_SCOPE_AGENT);
                    }
                }
                asm volatile("s_waitcnt vmcnt(0)" ::: "memory");
            }
        }
        __syncthreads();                       // the single per-step barrier
        if (abort_s) break;
        if (tid == 0)
            __hip_atomic_store(&flags[w*FSTR], (unsigned)(t + 2), __ATOMIC_RELAXED, __HIP_MEMORY_SCOPE_AGENT);
        if (((t+1) % NH_) == 0 && tid < NEEG) {        // off critical path
            float s = 0.f;
            #pragma unroll
            for (int jl = 0; jl < NJ; ++jl) s += lmt_l[tid][jl]*eim[jl];
            eeg_l[t/NH_][tid] = s;
        }
    }

    __syncthreads();
    if (!abort_s) {
        const float* el = &eeg_l[0][0];
        for (int idx = tid; idx < NB_*NEEG; idx += NT)
            __hip_atomic_fetch_add(&ws[OFF_EEG + idx], el[idx], __ATOMIC_RELAXED, __HIP_MEMORY_SCOPE_AGENT);
    }
}

__global__ void k_out(const float* __restrict__ ws, const float* __restrict__ theta,
                      float* __restrict__ out)
{
    int idx = blockIdx.x*256 + threadIdx.x;
    if (idx < NB_*NEEG) out[idx] = 0.01f*theta[13]*ws[OFF_EEG + idx] - theta[14];
}

extern "C" void kernel_launch(void* const* d_in, const int* in_sizes, int n_in,
                              void* d_out, int out_size, void* d_ws, size_t ws_size,
                              hipStream_t stream)
{
    const float* input    = (const float*)d_in[0];
    const float* noise_in = (const float*)d_in[1];
    const float* hx       = (const float*)d_in[3];
    const float* hE       = (const float*)d_in[4];
    const float* sc       = (const float*)d_in[5];
    const float* dist     = (const float*)d_in[6];
    const float* w_bb     = (const float*)d_in[7];
    const float* W_in     = (const float*)d_in[8];
    const float* lm       = (const float*)d_in[10];
    const float* theta    = (const float*)d_in[11];
    float* ws  = (float*)d_ws;
    float* out = (float*)d_out;

    hipMemsetAsync(d_ws, 0, OFF_ZEND*sizeof(float), stream);  // sumsq/abort/flags/rowsum/eeg/acc
    k_ws  <<<Nn, 256, 0, stream>>>(w_bb, sc, ws);
    k_lmt <<<(Nn + 255)/256, 256, 0, stream>>>(lm, ws);
    k_main<<<NWG, NT, 0, stream>>>(input, noise_in, hx, hE, dist, W_in, theta, ws);
    k_out <<<(NB_*NEEG + 255)/256, 256, 0, stream>>>(ws, theta, out);
}

// Round 4
// 1404.002 us; speedup vs baseline: 4.8297x; 1.3247x over previous
//
#include <hip/hip_runtime.h>
#include <math.h>

#define Nn     512
#define Ll     500
#define TSTEPS 800
#define NWG    32
#define NJ     16     // source nodes per workgroup
#define NT     320    // 5 waves: wave0 = control, waves 1-4 = gather
#define NEEG   64
#define NB_    40
#define NH_    20
#define ND0CAP 128

// d_ws layout in floats
#define OFF_SUMSQ  0
#define OFF_ABORT  1                    // u32
#define OFF_ND0IN  64                   // 512 u32
#define OFF_ROWSUM 576                  // 512 f32
#define OFF_EEG    1088                 // 2560 f32
#define OFF_ACC    4096                 // u64[4*512*8] lines (64B/target) = 32768 floats
#define OFF_ZEND   (OFF_ACC + 4*Nn*16)  // 36864
#define OFF_WS     36864                // 512*512
#define OFF_LMT    (OFF_WS + Nn*Nn)     // 64*512

__device__ __forceinline__ float relu_(float x) { return fmaxf(x, 0.0f); }

__device__ __forceinline__ unsigned long long enc_(float v) {
    long long q = (long long)llrintf(v * 1048576.0f);   // 2^20 fixed point
    return (1ULL << 40) + (unsigned long long)q;
}

__global__ void k_ws(const float* __restrict__ wbb, const float* __restrict__ sc,
                     float* __restrict__ ws)
{
    int i = blockIdx.x, tid = threadIdx.x;
    float rs = 0.f, sq = 0.f;
    for (int j = tid; j < Nn; j += 256) {
        float wij = expf(wbb[i*Nn+j]) * sc[i*Nn+j];
        float wji = expf(wbb[j*Nn+i]) * sc[j*Nn+i];
        float v = log1pf(0.5f*(wij + wji));
        ws[OFF_WS + i*Nn + j] = v;
        rs += v; sq += v*v;
    }
    #pragma unroll
    for (int off = 32; off > 0; off >>= 1) { rs += __shfl_down(rs, off); sq += __shfl_down(sq, off); }
    __shared__ float srs[4], ssq[4];
    int wv = tid >> 6, ln = tid & 63;
    if (ln == 0) { srs[wv] = rs; ssq[wv] = sq; }
    __syncthreads();
    if (tid == 0) {
        ws[OFF_ROWSUM + i] = srs[0]+srs[1]+srs[2]+srs[3];
        atomicAdd(&ws[OFF_SUMSQ], ssq[0]+ssq[1]+ssq[2]+ssq[3]);
    }
}

__global__ void k_lmt(const float* __restrict__ lm, float* __restrict__ ws)
{
    int n = blockIdx.x*256 + threadIdx.x;
    if (n >= Nn) return;
    float s = 0.f;
    for (int e = 0; e < NEEG; ++e) s += lm[e*Nn + n];
    float mean = s * (1.0f/NEEG);
    for (int e = 0; e < NEEG; ++e) ws[OFF_LMT + e*Nn + n] = lm[e*Nn + n] - mean;
}

// per-target count of delay-0 in-edges (same predicate as k_main's dd)
__global__ void k_prep(const float* __restrict__ dist, const float* __restrict__ theta,
                       float* __restrict__ ws)
{
    int j = blockIdx.x;
    float den = 1.5f + relu_(theta[15]);
    unsigned* nd0in = (unsigned*)ws + OFF_ND0IN;
    for (int i = threadIdx.x; i < Nn; i += 256)
        if ((int)(dist[j*Nn+i]/den) == 0) atomicAdd(&nd0in[i], 1u);
}

__global__ __launch_bounds__(NT) void k_main(
    const float* __restrict__ input, const float* __restrict__ noise_in,
    const float* __restrict__ hx, const float* __restrict__ hE,
    const float* __restrict__ dist, const float* __restrict__ W_in,
    const float* __restrict__ theta, float* __restrict__ ws)
{
    __shared__ float hist[NJ][512];          // 32 KB circular E-history
    __shared__ float wn[NJ][Nn];             // 32 KB weights (d0 zeroed before loop)
    __shared__ unsigned short dd[NJ][Nn];    // 16 KB delays
    __shared__ float u_l[TSTEPS*2];          // 6.4 KB stimulus
    __shared__ float lmt_l[NEEG][NJ];        // 4 KB
    __shared__ float eeg_l[NB_][NEEG];       // 10.2 KB
    __shared__ float eim[NJ];
    __shared__ int   d0_pk[ND0CAP];
    __shared__ float d0_w[ND0CAP];
    __shared__ int   nd0_s;
    __shared__ unsigned abort_s;

    const int w   = blockIdx.x;
    const int tid = threadIdx.x;
    const int j0  = w*NJ;
    float* histf  = &hist[0][0];

    float th[16];
    #pragma unroll
    for (int k = 0; k < 16; ++k) th[k] = theta[k];
    const float kg   = 0.01f + relu_(th[0]);
    const float kc1  = 0.01f + relu_(th[1]);
    const float kc2  = 0.01f + relu_(th[2]);
    const float kc3  = 0.01f + relu_(th[3]);
    const float kc4  = 0.01f + relu_(th[4]);
    const float kstd = 150.0f + relu_(th[5]);
    const float rA   = relu_(th[6]);
    const float aa   = 1.0f + relu_(th[7]);
    const float rB   = relu_(th[8]);
    const float ab   = 1.0f + relu_(th[9]);
    const float vmax = th[10], v0p = th[11], rr = th[12];
    const float den  = 1.5f + relu_(th[15]);
    const float invnorm = 1.0f / sqrtf(ws[OFF_SUMSQ]);

    if (tid == 0) { abort_s = 0u; nd0_s = 0; }

    for (int idx = tid; idx < NJ*Nn; idx += NT) {
        int jl = idx >> 9, i = idx & 511;
        int jg = j0 + jl;
        wn[jl][i] = ws[OFF_WS + jg*Nn + i] * invnorm;
        dd[jl][i] = (unsigned short)(int)(dist[jg*Nn + i] / den);
    }
    // slot s holds E(tau), s = tau mod 512; initial: tau=-1-k -> hE[:,k]
    for (int idx = tid; idx < NJ*512; idx += NT) {
        int jl = idx >> 9, s = idx & 511;
        int k = 511 - s;
        hist[jl][s] = (k < Ll) ? hE[(j0+jl)*Ll + k] : 0.0f;
    }
    for (int idx = tid; idx < TSTEPS*2; idx += NT) {
        int t = idx >> 1, s = idx & 1;
        int tt = (t % NH_)*NB_ + (t / NH_);
        u_l[idx] = input[tt*2 + s];
    }
    for (int idx = tid; idx < NEEG*NJ; idx += NT) {
        int e = idx / NJ, jl = idx - e*NJ;
        lmt_l[e][jl] = ws[OFF_LMT + e*Nn + j0 + jl];
    }
    // wave0 per-lane ODE state + params
    float stM=0,stE=0,stI=0,stMv=0,stEv=0,stIv=0, dgd_r=0, win0=0, win1=0;
    unsigned expc = 0;
    const float* nz_base = nullptr;
    if (tid < NJ) {
        stM  = hx[(j0+tid)*6+0]; stE  = hx[(j0+tid)*6+1]; stI  = hx[(j0+tid)*6+2];
        stMv = hx[(j0+tid)*6+3]; stEv = hx[(j0+tid)*6+4]; stIv = hx[(j0+tid)*6+5];
        dgd_r = -ws[OFF_ROWSUM + j0 + tid] * invnorm;
        win0 = W_in[(j0+tid)*2+0]; win1 = W_in[(j0+tid)*2+1];
        nz_base = noise_in + (size_t)(j0+tid)*(NH_*NB_*3);
        expc = 32u + ((const unsigned*)ws + OFF_ND0IN)[j0+tid];
    }
    __syncthreads();

    // d0 detection (record weight before masking)
    for (int idx = tid; idx < NJ*Nn; idx += NT) {
        int jl = idx >> 9, i = idx & 511;
        if (dd[jl][i] == 0) {
            int pos = atomicAdd(&nd0_s, 1);
            if (pos < ND0CAP) { d0_pk[pos] = (jl<<16) | i; d0_w[pos] = wn[jl][i]; }
        }
    }
    __syncthreads();
    const int nd0 = nd0_s;
    unsigned* abortf = (unsigned*)ws + OFF_ABORT;
    unsigned long long* accb = (unsigned long long*)(ws + OFF_ACC);
    if (nd0 > ND0CAP) {
        if (tid == 0) __hip_atomic_store(abortf, 1u, __ATOMIC_RELAXED, __HIP_MEMORY_SCOPE_AGENT);
        return;
    }
    for (int idx = tid; idx < nd0; idx += NT) {
        int pk = d0_pk[idx];
        wn[pk>>16][pk & 0xFFFF] = 0.f;       // mask d0 edges from bulk gather
    }
    __syncthreads();

    // gather-wave register preload + prologue publish (step 0, slot 0)
    float wnr0[NJ], wnr1[NJ];
    int   of0[NJ],  of1[NJ];
    if (tid >= 64) {
        const int gt = tid - 64;
        float p0 = 0.f, p1 = 0.f;
        #pragma unroll
        for (int jl = 0; jl < NJ; ++jl) {
            int da = (int)dd[jl][gt], db = (int)dd[jl][gt+256];
            wnr0[jl] = wn[jl][gt];  wnr1[jl] = wn[jl][gt+256];
            of0[jl] = (0 - da) & 511;  of1[jl] = (0 - db) & 511;
            p0 += wnr0[jl] * hist[jl][(511 - da) & 511];
            p1 += wnr1[jl] * hist[jl][(511 - db) & 511];
        }
        atomicAdd(&accb[(size_t)(0*Nn + gt      )*8], enc_(p0));
        atomicAdd(&accb[(size_t)(0*Nn + gt + 256)*8], enc_(p1));
    } else {
        for (int q = tid; q < nd0; q += 64) {     // d0 contributions to step 0 use E(-1)
            int pk = d0_pk[q];
            atomicAdd(&accb[(size_t)(0*Nn + (pk & 0xFFFF))*8],
                      enc_(d0_w[q] * hist[pk>>16][511]));
        }
    }

    auto step = [&](int t, unsigned long long& xp) -> bool {
        if (tid >= 64) {
            // ---- gather waves: bulk partials for step t+1 from registers ----
            if (t < TSTEPS-1) {
                const int gt = tid - 64;
                float g0 = 0.f, g1 = 0.f;
                #pragma unroll
                for (int jl = 0; jl < NJ; ++jl) {
                    g0 += wnr0[jl] * histf[jl*512 + of0[jl]];
                    g1 += wnr1[jl] * histf[jl*512 + of1[jl]];
                    of0[jl] = (of0[jl] + 1) & 511;
                    of1[jl] = (of1[jl] + 1) & 511;
                }
                unsigned long long* slot = accb + (size_t)((t+1)&3)*Nn*8;
                atomicAdd(&slot[(size_t)gt*8],        enc_(g0));
                atomicAdd(&slot[(size_t)(gt+256)*8],  enc_(g1));
            }
        } else {
            // ---- control wave ----
            float nz = 0.f;
            if (tid < NJ) nz = nz_base[((t % NH_)*NB_ + (t / NH_))*3];
            unsigned long long* line = accb + ((size_t)(t&3)*Nn + j0 + tid)*8;
            unsigned long long x = 0;
            bool mine = (tid < NJ);
            bool ok = !mine;
            int spins = 0;
            for (;;) {
                if (mine && !ok) {
                    x = __hip_atomic_load(line, __ATOMIC_RELAXED, __HIP_MEMORY_SCOPE_AGENT);
                    unsigned long long diff = x - xp;
                    ok = (((diff + (1ULL<<39)) >> 40) == (unsigned long long)expc);
                }
                if (__all(ok)) break;
                if ((++spins & 255) == 0) {
                    if (__hip_atomic_load(abortf, __ATOMIC_RELAXED, __HIP_MEMORY_SCOPE_AGENT) != 0u ||
                        spins > (1<<20)) {
                        __hip_atomic_store(abortf, 1u, __ATOMIC_RELAXED, __HIP_MEMORY_SCOPE_AGENT);
                        if ((tid & 63) == 0) abort_s = 1u;
                        break;
                    }
                }
            }
            if (abort_s == 0u) {
                if (mine) {
                    long long sv = (long long)((x - xp) - ((unsigned long long)expc << 40));
                    float LEd = (float)sv * (1.0f/1048576.0f);
                    xp = x;
                    float stim = win0*u_l[2*t] + win1*u_l[2*t+1];
                    float rM   = vmax / (1.0f + expf(-rr*((stE - stI) - v0p)));
                    float s1v  = vmax / (1.0f + expf(-rr*((kc1*stM)  - v0p)));
                    float s3v  = vmax / (1.0f + expf(-rr*((kc3*stM)  - v0p)));
                    float rE = kstd*nz + kg*(LEd + dgd_r*stE) + kc2*s1v;
                    float rI = kc4*s3v;
                    float nM = stM + 0.05f*stMv, nE = stE + 0.05f*stEv, nI = stI + 0.05f*stIv;
                    float nMv = stMv + 0.05f*(rA*aa*(500.0f*tanhf(rM*0.002f)) - 2.0f*aa*stMv - aa*aa*stM);
                    float nEv = stEv + 0.05f*(rA*aa*(stim + 500.0f*tanhf(rE*0.002f)) - 2.0f*aa*stEv - aa*aa*stE);
                    float nIv = stIv + 0.05f*(rB*ab*(500.0f*tanhf(rI*0.002f)) - 2.0f*ab*stIv - ab*ab*stI);
                    stM = nM; stE = nE; stI = nI; stMv = nMv; stEv = nEv; stIv = nIv;
                    hist[tid][t & 511] = nE;
                    if (((t+1) % NH_) == 0) eim[tid] = nE - nI;
                }
                // latency-critical: d0 contributions to step t+1 with fresh E(t)
                if (t < TSTEPS-1) {
                    unsigned long long* slotN = accb + (size_t)((t+1)&3)*Nn*8;
                    for (int q = tid; q < nd0; q += 64) {
                        int pk = d0_pk[q];
                        atomicAdd(&slotN[(size_t)(pk & 0xFFFF)*8],
                                  enc_(d0_w[q] * hist[pk>>16][t & 511]));
                    }
                }
            }
        }
        __syncthreads();
        bool ab = (abort_s != 0u);
        if (!ab && ((t+1) % NH_) == 0 && tid < NEEG) {
            float s = 0.f;
            #pragma unroll
            for (int jl = 0; jl < NJ; ++jl) s += lmt_l[tid][jl]*eim[jl];
            eeg_l[t/NH_][tid] = s;
        }
        return ab;
    };

    unsigned long long xp0 = 0, xp1 = 0, xp2 = 0, xp3 = 0;
    for (int tb = 0; tb < TSTEPS; tb += 4) {
        if (step(tb+0, xp0)) break;
        if (step(tb+1, xp1)) break;
        if (step(tb+2, xp2)) break;
        if (step(tb+3, xp3)) break;
    }

    __syncthreads();
    if (abort_s == 0u) {
        const float* el = &eeg_l[0][0];
        for (int idx = tid; idx < NB_*NEEG; idx += NT)
            atomicAdd(&ws[OFF_EEG + idx], el[idx]);
    }
}

__global__ void k_out(const float* __restrict__ ws, const float* __restrict__ theta,
                      float* __restrict__ out)
{
    int idx = blockIdx.x*256 + threadIdx.x;
    if (idx < NB_*NEEG) out[idx] = 0.01f*theta[13]*ws[OFF_EEG + idx] - theta[14];
}

extern "C" void kernel_launch(void* const* d_in, const int* in_sizes, int n_in,
                              void* d_out, int out_size, void* d_ws, size_t ws_size,
                              hipStream_t stream)
{
    const float* input    = (const float*)d_in[0];
    const float* noise_in = (const float*)d_in[1];
    const float* hx       = (const float*)d_in[3];
    const float* hE       = (const float*)d_in[4];
    const float* sc       = (const float*)d_in[5];
    const float* dist     = (const float*)d_in[6];
    const float* w_bb     = (const float*)d_in[7];
    const float* W_in     = (const float*)d_in[8];
    const float* lm       = (const float*)d_in[10];
    const float* theta    = (const float*)d_in[11];
    float* ws  = (float*)d_ws;
    float* out = (float*)d_out;

    hipMemsetAsync(d_ws, 0, OFF_ZEND*sizeof(float), stream);
    k_ws  <<<Nn, 256, 0, stream>>>(w_bb, sc, ws);
    k_lmt <<<(Nn + 255)/256, 256, 0, stream>>>(lm, ws);
    k_prep<<<Nn, 256, 0, stream>>>(dist, theta, ws);
    k_main<<<NWG, NT, 0, stream>>>(input, noise_in, hx, hE, dist, W_in, theta, ws);
    k_out <<<(NB_*NEEG + 255)/256, 256, 0, stream>>>(ws, theta, out);
}

// Round 5
// 1223.515 us; speedup vs baseline: 5.5422x; 1.1475x over previous
//
#include <hip/hip_runtime.h>
#include <math.h>

#define Nn     512
#define Ll     500
#define TSTEPS 800
#define NWG    32
#define NJ     16     // source nodes per workgroup
#define NT     320    // 5 waves: wave0 = control, waves 1-4 = gather
#define NEEG   64
#define NB_    40
#define NH_    20
#define SCALE_    524288.0f        // 2^19 fixed point
#define INVSCALE_ (1.0f/524288.0f)

// d_ws layout in floats
#define OFF_SUMSQ  0
#define OFF_ABORT  1                      // u32
#define OFF_ROWSUM 64                     // 512 f32
#define OFF_EEG    576                    // 2560 f32
#define OFF_ZEND   3200                   // zero [0, OFF_ZEND)
#define OFF_TBUF   3200                   // u32[3 * 512 * 32] tagged exchange
#define TBUF_WORDS (3*Nn*NWG)             // 49152
#define OFF_WS     (OFF_TBUF + TBUF_WORDS)    // 52352
#define OFF_LMT    (OFF_WS + Nn*Nn)           // + 64*512

__device__ __forceinline__ float relu_(float x) { return fmaxf(x, 0.0f); }

__global__ void k_ws(const float* __restrict__ wbb, const float* __restrict__ sc,
                     float* __restrict__ ws)
{
    int i = blockIdx.x, tid = threadIdx.x;
    float rs = 0.f, sq = 0.f;
    for (int j = tid; j < Nn; j += 256) {
        float wij = expf(wbb[i*Nn+j]) * sc[i*Nn+j];
        float wji = expf(wbb[j*Nn+i]) * sc[j*Nn+i];
        float v = log1pf(0.5f*(wij + wji));
        ws[OFF_WS + i*Nn + j] = v;
        rs += v; sq += v*v;
    }
    #pragma unroll
    for (int off = 32; off > 0; off >>= 1) { rs += __shfl_down(rs, off); sq += __shfl_down(sq, off); }
    __shared__ float srs[4], ssq[4];
    int wv = tid >> 6, ln = tid & 63;
    if (ln == 0) { srs[wv] = rs; ssq[wv] = sq; }
    __syncthreads();
    if (tid == 0) {
        ws[OFF_ROWSUM + i] = srs[0]+srs[1]+srs[2]+srs[3];
        atomicAdd(&ws[OFF_SUMSQ], ssq[0]+ssq[1]+ssq[2]+ssq[3]);
    }
}

__global__ void k_lmt(const float* __restrict__ lm, float* __restrict__ ws)
{
    int n = blockIdx.x*256 + threadIdx.x;
    if (n >= Nn) return;
    float s = 0.f;
    for (int e = 0; e < NEEG; ++e) s += lm[e*Nn + n];
    float mean = s * (1.0f/NEEG);
    for (int e = 0; e < NEEG; ++e) ws[OFF_LMT + e*Nn + n] = lm[e*Nn + n] - mean;
}

__global__ __launch_bounds__(NT) void k_main(
    const float* __restrict__ input, const float* __restrict__ noise_in,
    const float* __restrict__ hx, const float* __restrict__ hE,
    const float* __restrict__ dist, const float* __restrict__ W_in,
    const float* __restrict__ theta, float* __restrict__ ws)
{
    __shared__ float hist[NJ][512];          // 32 KB circular E-history
    __shared__ float wn[NJ][Nn];             // 32 KB weights (full, incl. delay-0)
    __shared__ unsigned short dd[NJ][Nn];    // 16 KB delays
    __shared__ float u_l[TSTEPS*2];          // 6.4 KB stimulus
    __shared__ float lmt_l[NEEG][NJ];        // 4 KB
    __shared__ float eeg_l[NB_][NEEG];       // 10.2 KB
    __shared__ float eim[NJ];
    __shared__ unsigned abort_s;

    const int w   = blockIdx.x;
    const int tid = threadIdx.x;
    const int j0  = w*NJ;
    float* histf  = &hist[0][0];

    float th[16];
    #pragma unroll
    for (int k = 0; k < 16; ++k) th[k] = theta[k];
    const float kg   = 0.01f + relu_(th[0]);
    const float kc1  = 0.01f + relu_(th[1]);
    const float kc2  = 0.01f + relu_(th[2]);
    const float kc3  = 0.01f + relu_(th[3]);
    const float kc4  = 0.01f + relu_(th[4]);
    const float kstd = 150.0f + relu_(th[5]);
    const float rA   = relu_(th[6]);
    const float aa   = 1.0f + relu_(th[7]);
    const float rB   = relu_(th[8]);
    const float ab   = 1.0f + relu_(th[9]);
    const float vmax = th[10], v0p = th[11], rr = th[12];
    const float den  = 1.5f + relu_(th[15]);
    const float invnorm = 1.0f / sqrtf(ws[OFF_SUMSQ]);

    if (tid == 0) abort_s = 0u;

    for (int idx = tid; idx < NJ*Nn; idx += NT) {
        int jl = idx >> 9, i = idx & 511;
        int jg = j0 + jl;
        wn[jl][i] = ws[OFF_WS + jg*Nn + i] * invnorm;
        dd[jl][i] = (unsigned short)(int)(dist[jg*Nn + i] / den);
    }
    // slot s holds E(tau), s = tau mod 512; initial: tau=-1-k -> hE[:,k]
    for (int idx = tid; idx < NJ*512; idx += NT) {
        int jl = idx >> 9, s = idx & 511;
        int k = 511 - s;
        hist[jl][s] = (k < Ll) ? hE[(j0+jl)*Ll + k] : 0.0f;
    }
    for (int idx = tid; idx < TSTEPS*2; idx += NT) {
        int t = idx >> 1, s = idx & 1;
        int tt = (t % NH_)*NB_ + (t / NH_);
        u_l[idx] = input[tt*2 + s];
    }
    for (int idx = tid; idx < NEEG*NJ; idx += NT) {
        int e = idx / NJ, jl = idx - e*NJ;
        lmt_l[e][jl] = ws[OFF_LMT + e*Nn + j0 + jl];
    }
    // wave0 per-lane ODE state + params
    float stM=0,stE=0,stI=0,stMv=0,stEv=0,stIv=0, dgd_r=0, win0=0, win1=0;
    const float* nz_base = nullptr;
    if (tid < NJ) {
        stM  = hx[(j0+tid)*6+0]; stE  = hx[(j0+tid)*6+1]; stI  = hx[(j0+tid)*6+2];
        stMv = hx[(j0+tid)*6+3]; stEv = hx[(j0+tid)*6+4]; stIv = hx[(j0+tid)*6+5];
        dgd_r = -ws[OFF_ROWSUM + j0 + tid] * invnorm;
        win0 = W_in[(j0+tid)*2+0]; win1 = W_in[(j0+tid)*2+1];
        nz_base = noise_in + (size_t)(j0+tid)*(NH_*NB_*3);
    }
    __syncthreads();

    unsigned* tbuf   = (unsigned*)ws + OFF_TBUF;
    unsigned* abortf = (unsigned*)ws + OFF_ABORT;

    // gather-wave register preload + prologue publish (step 0 -> buffer 0, tag 0)
    float wnr0[NJ], wnr1[NJ];
    int   of0[NJ],  of1[NJ];
    if (tid >= 64) {
        const int gt = tid - 64;
        float p0 = 0.f, p1 = 0.f;
        #pragma unroll
        for (int jl = 0; jl < NJ; ++jl) {
            int da = (int)dd[jl][gt], db = (int)dd[jl][gt+256];
            wnr0[jl] = wn[jl][gt];  wnr1[jl] = wn[jl][gt+256];
            of0[jl] = (0 - da) & 511;  of1[jl] = (0 - db) & 511;
            p0 += wnr0[jl] * hist[jl][(511 - da) & 511];
            p1 += wnr1[jl] * hist[jl][(511 - db) & 511];
        }
        int q0 = (int)lrintf(p0*SCALE_), q1 = (int)lrintf(p1*SCALE_);
        const int i0 = gt, i1 = gt + 256;
        __hip_atomic_store(&tbuf[((i0>>4)<<9) + ((i0&15)<<5) + w], (unsigned)q0 & 0x1FFFFFFu,
                           __ATOMIC_RELAXED, __HIP_MEMORY_SCOPE_AGENT);
        __hip_atomic_store(&tbuf[((i1>>4)<<9) + ((i1&15)<<5) + w], (unsigned)q1 & 0x1FFFFFFu,
                           __ATOMIC_RELAXED, __HIP_MEMORY_SCOPE_AGENT);
    }

    for (int t = 0; t < TSTEPS; ++t) {
        // ---- early phase: positions are coupling-independent ----
        float nM_pre=0.f, nE_pre=0.f, nI_pre=0.f;
        if (tid < NJ) {
            nM_pre = stM + 0.05f*stMv;
            nE_pre = stE + 0.05f*stEv;
            nI_pre = stI + 0.05f*stIv;
            hist[tid][t & 511] = nE_pre;
            if (((t+1) % NH_) == 0) eim[tid] = nE_pre - nI_pre;
        }
        __syncthreads();                              // B1: hist[t] visible

        if (tid >= 64) {
            // ---- gather waves: full partials (incl. d0) for step t+1, tagged stores ----
            const int gt = tid - 64;
            float g0 = 0.f, g1 = 0.f;
            #pragma unroll
            for (int jl = 0; jl < NJ; ++jl) {
                g0 += wnr0[jl] * histf[jl*512 + of0[jl]];
                g1 += wnr1[jl] * histf[jl*512 + of1[jl]];
                of0[jl] = (of0[jl] + 1) & 511;
                of1[jl] = (of1[jl] + 1) & 511;
            }
            if (t < TSTEPS-1) {
                const unsigned tg = (unsigned)((t+1) & 127) << 25;
                unsigned* bufn = tbuf + ((t+1) % 3)*(Nn*NWG);
                int q0 = (int)lrintf(g0*SCALE_), q1 = (int)lrintf(g1*SCALE_);
                const int i0 = gt, i1 = gt + 256;
                __hip_atomic_store(&bufn[((i0>>4)<<9) + ((i0&15)<<5) + w], tg | ((unsigned)q0 & 0x1FFFFFFu),
                                   __ATOMIC_RELAXED, __HIP_MEMORY_SCOPE_AGENT);
                __hip_atomic_store(&bufn[((i1>>4)<<9) + ((i1&15)<<5) + w], tg | ((unsigned)q1 & 0x1FFFFFFu),
                                   __ATOMIC_RELAXED, __HIP_MEMORY_SCOPE_AGENT);
            }
            // wave 1: EEG dot at inner-scan boundary (reads eim written pre-B1)
            if (((t+1) % NH_) == 0 && tid < 128) {
                int e = tid - 64;
                float s = 0.f;
                #pragma unroll
                for (int jl = 0; jl < NJ; ++jl) s += lmt_l[e][jl]*eim[jl];
                eeg_l[t/NH_][e] = s;
            }
        } else {
            // ---- control wave ----
            float nz = 0.f, stim = 0.f, rE0 = 0.f, nMv = 0.f, nIv = 0.f;
            if (tid < NJ) {
                nz = nz_base[((t % NH_)*NB_ + (t / NH_))*3];        // in flight during poll
                stim = win0*u_l[2*t] + win1*u_l[2*t+1];
                float rM  = vmax / (1.0f + expf(-rr*((stE - stI) - v0p)));
                float s1v = vmax / (1.0f + expf(-rr*((kc1*stM)  - v0p)));
                float s3v = vmax / (1.0f + expf(-rr*((kc3*stM)  - v0p)));
                float rI  = kc4*s3v;
                rE0 = kg*(dgd_r*stE) + kc2*s1v;                     // + kstd*nz + kg*LEd later
                nMv = stMv + 0.05f*(rA*aa*(500.0f*tanhf(rM*0.002f)) - 2.0f*aa*stMv - aa*aa*stM);
                nIv = stIv + 0.05f*(rB*ab*(500.0f*tanhf(rI*0.002f)) - 2.0f*ab*stIv - ab*ab*stI);
            }
            // poll own 512 tagged words (8 u32 per lane, as 4 u64 loads)
            const unsigned tg = (unsigned)(t & 127);
            const unsigned long long* pl =
                (const unsigned long long*)(tbuf + (t % 3)*(Nn*NWG) + w*512) + (size_t)tid*4;
            unsigned long long a0, a1, a2, a3;
            bool timeout = false;
            unsigned spins = 0;
            for (;;) {
                a0 = __hip_atomic_load(pl+0, __ATOMIC_RELAXED, __HIP_MEMORY_SCOPE_AGENT);
                a1 = __hip_atomic_load(pl+1, __ATOMIC_RELAXED, __HIP_MEMORY_SCOPE_AGENT);
                a2 = __hip_atomic_load(pl+2, __ATOMIC_RELAXED, __HIP_MEMORY_SCOPE_AGENT);
                a3 = __hip_atomic_load(pl+3, __ATOMIC_RELAXED, __HIP_MEMORY_SCOPE_AGENT);
                bool ok = (((a0>>25)&127)==tg) && (((a0>>57)&127)==tg)
                       && (((a1>>25)&127)==tg) && (((a1>>57)&127)==tg)
                       && (((a2>>25)&127)==tg) && (((a2>>57)&127)==tg)
                       && (((a3>>25)&127)==tg) && (((a3>>57)&127)==tg);
                if (__all(ok)) break;
                if ((++spins & 255u) == 0u) {
                    if (__hip_atomic_load(abortf, __ATOMIC_RELAXED, __HIP_MEMORY_SCOPE_AGENT) != 0u ||
                        spins > (1u<<22)) { timeout = true; break; }
                }
            }
            if (timeout) {
                __hip_atomic_store(abortf, 1u, __ATOMIC_RELAXED, __HIP_MEMORY_SCOPE_AGENT);
                if (tid == 0) abort_s = 1u;
            } else {
                int qs = ((int)(((unsigned)(a0      )) << 7) >> 7) + ((int)(((unsigned)(a0>>32)) << 7) >> 7)
                       + ((int)(((unsigned)(a1      )) << 7) >> 7) + ((int)(((unsigned)(a1>>32)) << 7) >> 7)
                       + ((int)(((unsigned)(a2      )) << 7) >> 7) + ((int)(((unsigned)(a2>>32)) << 7) >> 7)
                       + ((int)(((unsigned)(a3      )) << 7) >> 7) + ((int)(((unsigned)(a3>>32)) << 7) >> 7);
                qs += __shfl_xor(qs, 1);
                qs += __shfl_xor(qs, 2);
                int qtot = __shfl(qs, (tid & 15)*4);
                if (tid < NJ) {
                    float LEd = (float)qtot * INVSCALE_;
                    float rE = rE0 + kstd*nz + kg*LEd;
                    float nEv = stEv + 0.05f*(rA*aa*(stim + 500.0f*tanhf(rE*0.002f)) - 2.0f*aa*stEv - aa*aa*stE);
                    stM = nM_pre; stE = nE_pre; stI = nI_pre;
                    stMv = nMv; stEv = nEv; stIv = nIv;
                }
            }
        }
        __syncthreads();                              // B2
        if (abort_s) break;
    }

    __syncthreads();
    if (abort_s == 0u) {
        const float* el = &eeg_l[0][0];
        for (int idx = tid; idx < NB_*NEEG; idx += NT)
            atomicAdd(&ws[OFF_EEG + idx], el[idx]);
    }
}

__global__ void k_out(const float* __restrict__ ws, const float* __restrict__ theta,
                      float* __restrict__ out)
{
    int idx = blockIdx.x*256 + threadIdx.x;
    if (idx < NB_*NEEG) out[idx] = 0.01f*theta[13]*ws[OFF_EEG + idx] - theta[14];
}

extern "C" void kernel_launch(void* const* d_in, const int* in_sizes, int n_in,
                              void* d_out, int out_size, void* d_ws, size_t ws_size,
                              hipStream_t stream)
{
    const float* input    = (const float*)d_in[0];
    const float* noise_in = (const float*)d_in[1];
    const float* hx       = (const float*)d_in[3];
    const float* hE       = (const float*)d_in[4];
    const float* sc       = (const float*)d_in[5];
    const float* dist     = (const float*)d_in[6];
    const float* w_bb     = (const float*)d_in[7];
    const float* W_in     = (const float*)d_in[8];
    const float* lm       = (const float*)d_in[10];
    const float* theta    = (const float*)d_in[11];
    float* ws  = (float*)d_ws;
    float* out = (float*)d_out;

    hipMemsetAsync(d_ws, 0, OFF_ZEND*sizeof(float), stream);                       // hdr+eeg
    hipMemsetAsync((char*)d_ws + (size_t)OFF_TBUF*4, 0xFF, (size_t)TBUF_WORDS*4,   // tags=127
                   stream);
    k_ws  <<<Nn, 256, 0, stream>>>(w_bb, sc, ws);
    k_lmt <<<(Nn + 255)/256, 256, 0, stream>>>(lm, ws);
    k_main<<<NWG, NT, 0, stream>>>(input, noise_in, hx, hE, dist, W_in, theta, ws);
    k_out <<<(NB_*NEEG + 255)/256, 256, 0, stream>>>(ws, theta, out);
}